// Round 12
// baseline (430.981 us; speedup 1.0000x reference)
//
#include <hip/hip_runtime.h>
#include <stdint.h>

// Self-attention, SEQ=8192, D=768, single head.
//   K0 : fused convert x/Wq/Wk/Wv fp32->bf16 (one launch)
//   K1 : fused Q,K,Vt projections, z=3 (128^2 engine, MODE 0)
//   K2 : P' = exp(Q K^T) bf16 + rowsums     (256^2 8-phase engine)
//   K3 : out += (P' V)/rowsum, split-K x8   (128^2 engine, MODE 2)  <- R22
//
// R22 = R20 restored (T1 swizzle REVERTED) + K3 KSPLIT 4->8.
// R21 post-mortem: T1 swizzle BACKFIRED on K3 (FETCH 167->399 MB,
// 156->175 us). With gx=64 (%8==0), the DEFAULT round-robin already
// co-locates the 6 blocks sharing one P-row-slice (same bx, by differs
// by multiples of 64) on one XCD -> perfect big-tensor locality. The
// swizzle instead streamed the whole 33 MB P z-slice through each 4 MB
// L2 (399 = 134 x ~3 re-fetches). RULE: check gx%8 before applying T1;
// default mapping is already panel-local when gx%8==0.
// This round's experiment: K3 grid 1536 blocks @4-resident = 1024 slots
// = 1.5 lockstep rounds = ~75% utilization (measured Occ 36% vs 50%
// packed). KSPLIT=8 -> 3072 blocks = exactly 3 full rounds. Cost:
// atomic WRITE 98->197 MB (overlapped; R18's atomic penalty was
// 1-residency exposure, we stay 4-resident), prologue x1.5.

#define SEQ    8192
#define DMODEL 768
#define KSPLIT 8             // split-K for K3: 64x6x8=3072 = 3 exact rounds
#define LROW   64            // 128^2 engine LDS row stride (halfwords)

typedef short bf16x8 __attribute__((ext_vector_type(8)));
typedef float f32x4  __attribute__((ext_vector_type(4)));
typedef float f32x16 __attribute__((ext_vector_type(16)));

__device__ __forceinline__ unsigned short f2bf(float f) {
  union { float f; unsigned int u; } v; v.f = f;
  unsigned int u = v.u;
  u += 0x7FFFu + ((u >> 16) & 1u);   // round-to-nearest-even
  return (unsigned short)(u >> 16);
}

// global -> LDS direct DMA, 16 B/lane; LDS dest wave-uniform + lane*16 (m104).
__device__ __forceinline__ void gload16(const unsigned short* g, unsigned short* l) {
  __builtin_amdgcn_global_load_lds(
      (const __attribute__((address_space(1))) unsigned int*)g,
      (__attribute__((address_space(3))) unsigned int*)l, 16, 0, 0);
}

// Stage one half-tile (128x64 bf16 = 16 KB): 512 thr x 2 x 16 B.
// LDS linear; source column pre-swizzled (slot j <- col j^(row&7)).
__device__ __forceinline__ void stage_ht(const unsigned short* __restrict__ g,
                                         int Kd, unsigned short* l, int t) {
  const int c0 = t, c1 = t + 512;
  const int r0 = c0 >> 3, r1 = c1 >> 3;
  const int s0 = ((c0 & 7) ^ (r0 & 7)) << 3;
  const int s1 = ((c1 & 7) ^ (r1 & 7)) << 3;
  gload16(g + (size_t)r0 * Kd + s0, l + (c0 << 3));
  gload16(g + (size_t)r1 * Kd + s1, l + (c1 << 3));
}

// K0: all four fp32->bf16 converts in one launch, range-decoded.
__global__ void convert_all(const float* __restrict__ x,  const float* __restrict__ Wq,
                            const float* __restrict__ Wk, const float* __restrict__ Wv,
                            unsigned short* __restrict__ xb,  unsigned short* __restrict__ wqb,
                            unsigned short* __restrict__ wkb, unsigned short* __restrict__ wvb) {
  const int NX = SEQ * DMODEL / 4;        // float4 count for x
  const int NW = DMODEL * DMODEL / 4;     // per weight
  int i = blockIdx.x * blockDim.x + threadIdx.x;
  const float* s; unsigned short* d; int off;
  if (i < NX)                { s = x;  d = xb;  off = i; }
  else if (i < NX + NW)      { s = Wq; d = wqb; off = i - NX; }
  else if (i < NX + 2 * NW)  { s = Wk; d = wkb; off = i - NX - NW; }
  else if (i < NX + 3 * NW)  { s = Wv; d = wvb; off = i - NX - 2 * NW; }
  else return;
  const float4 f = ((const float4*)s)[off];
  ushort4 o;
  o.x = f2bf(f.x); o.y = f2bf(f.y); o.z = f2bf(f.z); o.w = f2bf(f.w);
  ((ushort4*)d)[off] = o;
}

// ---------------- 256^2 8-phase engine (K2) ----------------
// C[m,n]=sum_k A[m,k]B[n,k]; writes exp(C) bf16 + atomic rowsums.
// 8 waves (2M x 4N); MFMA 16x16x32: A/B frag lane row=l&15, k=(l>>4)*8+j;
// C/D col=l&15, row=(l>>4)*4+reg [m89/m91].
// LDS halfwords: [dbuf2][tensor2][half2][128][64]=65536 (128 KB).
// Schedule (verified R17: K2 164->129 us): phases (qa, b-half) per K-tile,
// reads-once-into-regs, one 16KB stage/phase, vmcnt(6) only at ph4/ph8.
__launch_bounds__(512, 2)
__global__ void gemm256_exp(const unsigned short* __restrict__ A,
                            const unsigned short* __restrict__ B,
                            unsigned short* __restrict__ C,
                            int N, int K, float* __restrict__ rowsum) {
  __shared__ __align__(16) unsigned short lds[65536];
  const int t    = threadIdx.x;
  const int w    = t >> 6, l = t & 63;
  const int lr   = l & 15, lq = l >> 4;
  const int wrow = w >> 2, wcol = w & 3;
  const int m0   = blockIdx.x * 256;
  const int n0   = blockIdx.y * 256;
  const unsigned short* Ab = A + (size_t)m0 * K;
  const unsigned short* Bb = B + (size_t)n0 * K;

  const int rA64 = (wrow * 64 + lr) * 64;
  const int rB64 = (wcol * 32 + lr) * 64;
  const int x7   = lr & 7;
  const int csw0 = ((0 + lq) ^ x7) << 3;   // ks=0 chunk
  const int csw1 = ((4 + lq) ^ x7) << 3;   // ks=1 chunk

  f32x4 acc[2][2][4][2] = {};              // [qa][bh][rt][ct]
  const int nt = K >> 6, ni = nt >> 1;

#define STG(T, H, D, JT) stage_ht(((T) ? Bb : Ab) + (size_t)((H) * 128) * K + (JT) * 64, K, \
                                  &lds[(D) * 32768 + (T) * 16384 + (H) * 8192], t)
#define RDA(D, QA) do { \
    _Pragma("unroll") for (int rt = 0; rt < 4; ++rt) { \
      a[rt][0] = *(const bf16x8*)&lds[(D)*32768 + (QA)*8192 + rA64 + rt*1024 + csw0]; \
      a[rt][1] = *(const bf16x8*)&lds[(D)*32768 + (QA)*8192 + rA64 + rt*1024 + csw1]; \
    } } while (0)
#define RDB(D, BH, DST) do { \
    _Pragma("unroll") for (int ct = 0; ct < 2; ++ct) { \
      DST[ct][0] = *(const bf16x8*)&lds[(D)*32768 + 16384 + (BH)*8192 + rB64 + ct*1024 + csw0]; \
      DST[ct][1] = *(const bf16x8*)&lds[(D)*32768 + 16384 + (BH)*8192 + rB64 + ct*1024 + csw1]; \
    } } while (0)
#define MM16(QA, BH, BR) do { \
    __builtin_amdgcn_s_setprio(1); \
    _Pragma("unroll") for (int ks = 0; ks < 2; ++ks) \
      _Pragma("unroll") for (int rt = 0; rt < 4; ++rt) \
        _Pragma("unroll") for (int ct = 0; ct < 2; ++ct) \
          acc[QA][BH][rt][ct] = __builtin_amdgcn_mfma_f32_16x16x32_bf16( \
              a[rt][ks], BR[ct][ks], acc[QA][BH][rt][ct], 0, 0, 0); \
    __builtin_amdgcn_s_setprio(0); \
  } while (0)
#define WAITV6() asm volatile("s_waitcnt vmcnt(6)" ::: "memory")
#define WAITV0() asm volatile("s_waitcnt vmcnt(0)" ::: "memory")
#define LGKM0()  asm volatile("s_waitcnt lgkmcnt(0)" ::: "memory")
#define BAR()    __builtin_amdgcn_s_barrier()

  bf16x8 a[4][2], b0[2][2], b1[2][2];

  // Prologue: tile0 (A0,B0,B1,A1)->d0, tile1 (A0,B0,B1)->d1; drain to 3.
  STG(0, 0, 0, 0); STG(1, 0, 0, 0); STG(1, 1, 0, 0); STG(0, 1, 0, 0);
  STG(0, 0, 1, 1); STG(1, 0, 1, 1); STG(1, 1, 1, 1);
  WAITV6(); BAR();

  for (int i = 0; i < ni; ++i) {
    const int j = 2 * i;
    const bool full = (i + 1 < ni);
    // ph1 (d0, qa0, b0): 12 reads; stage d1.A1(j+1)
    RDA(0, 0); RDB(0, 0, b0); STG(0, 1, 1, j + 1);
    BAR(); LGKM0(); MM16(0, 0, b0); BAR();
    // ph2 (d0, qa0, b1): 4 reads; stage d0.A0(j+2)
    RDB(0, 1, b1); if (full) STG(0, 0, 0, j + 2);
    BAR(); LGKM0(); MM16(0, 1, b1); BAR();
    // ph3 (d0, qa1, b0): 8 reads; stage d0.B0(j+2)
    RDA(0, 1); if (full) STG(1, 0, 0, j + 2);
    BAR(); LGKM0(); MM16(1, 0, b0); BAR();
    // ph4 (d0, qa1, b1): 0 reads; stage d0.B1(j+2); counted wait AFTER MFMA
    if (full) STG(1, 1, 0, j + 2);
    BAR(); MM16(1, 1, b1);
    if (full) { WAITV6(); } else { WAITV0(); }
    BAR();
    // ph5 (d1, qa0, b0): 12 reads; stage d0.A1(j+2)
    RDA(1, 0); RDB(1, 0, b0); if (full) STG(0, 1, 0, j + 2);
    BAR(); LGKM0(); MM16(0, 0, b0); BAR();
    // ph6 (d1, qa0, b1): 4 reads; stage d1.A0(j+3)
    RDB(1, 1, b1); if (full) STG(0, 0, 1, j + 3);
    BAR(); LGKM0(); MM16(0, 1, b1); BAR();
    // ph7 (d1, qa1, b0): 8 reads; stage d1.B0(j+3)
    RDA(1, 1); if (full) STG(1, 0, 1, j + 3);
    BAR(); LGKM0(); MM16(1, 0, b0); BAR();
    // ph8 (d1, qa1, b1): 0 reads; stage d1.B1(j+3); counted wait
    if (full) STG(1, 1, 1, j + 3);
    BAR(); MM16(1, 1, b1);
    if (full) WAITV6();
    BAR();
  }

  // Epilogue: exp + bf16 store + per-row exp-sum (16-lane groups share m).
#pragma unroll
  for (int qa = 0; qa < 2; ++qa)
#pragma unroll
    for (int rt = 0; rt < 4; ++rt)
#pragma unroll
      for (int reg = 0; reg < 4; ++reg) {
        const int m = m0 + qa * 128 + wrow * 64 + rt * 16 + lq * 4 + reg;
        float s = 0.f;
#pragma unroll
        for (int bh = 0; bh < 2; ++bh)
#pragma unroll
          for (int ct = 0; ct < 2; ++ct) {
            const int n = n0 + bh * 128 + wcol * 32 + ct * 16 + lr;
            float p = __expf(acc[qa][bh][rt][ct][reg]);
            C[(size_t)m * N + n] = f2bf(p);
            s += p;
          }
#pragma unroll
        for (int off = 1; off < 16; off <<= 1) s += __shfl_xor(s, off, 64);
        if (lr == 0) atomicAdd(&rowsum[m], s);
      }
#undef STG
#undef RDA
#undef RDB
#undef MM16
#undef WAITV6
#undef WAITV0
#undef LGKM0
#undef BAR
}

// ---------------- 128^2 2-barrier engine (K1 fused / K3) ----------------
// MODE 0 (fused QKV projections, all K=768):
//   z=0: C = A·B^T       (Q = x Wq^T, alpha=1/sqrt(768), N=768)
//   z=1: C = A·B2^T      (K = x Wk^T, alpha=1, N=768)
//   z=2: C = A3·A^T      (Vt = Wv x^T, alpha=1, N=8192; bx/by swapped)
// MODE 2: split-K over z (kChunk each); atomicAdd fp32 C/rowsum[m] into Cout
template <int MODE>
__launch_bounds__(256, 4)
__global__ void gemm_bt(const unsigned short* __restrict__ A,
                        const unsigned short* __restrict__ B,
                        void* __restrict__ Cout,
                        int M, int N, int K, float alpha,
                        float* __restrict__ rowsum, int kChunk,
                        const unsigned short* __restrict__ B2,
                        void* __restrict__ Cout2, float alpha2,
                        const unsigned short* __restrict__ A3,
                        void* __restrict__ Cout3) {
  __shared__ __align__(16) unsigned short lA[128 * LROW];
  __shared__ __align__(16) unsigned short lB[128 * LROW];

  int bx = blockIdx.x, by = blockIdx.y;
  if (MODE == 0) {
    if (blockIdx.z == 1) { B = B2; Cout = Cout2; alpha = alpha2; }
    else if (blockIdx.z == 2) {
      B = A; A = A3; Cout = Cout3; alpha = 1.0f; N = SEQ;
      int tmp = bx; bx = by; by = tmp;   // m-tiles over 768, n-tiles over 8192
    }
  }
  const int kOff = (MODE == 2) ? blockIdx.z * kChunk : 0;

  const int t    = threadIdx.x;
  const int w    = t >> 6;
  const int l    = t & 63;
  const int r32  = l & 31;
  const int kh   = l >> 5;
  const int m0   = bx * 128;
  const int n0   = by * 128;
  const int wm   = (w & 1) * 64;
  const int wn   = (w >> 1) * 64;

  int gOff[4], dOff[4];
#pragma unroll
  for (int h = 0; h < 4; ++h) {
    int c   = t + (h << 8);
    int row = c >> 3;
    int j   = c & 7;
    gOff[h] = row * K + ((j ^ (row & 7)) << 3);
    dOff[h] = c << 3;
  }
  const unsigned short* Abase = A + (size_t)m0 * K + kOff;
  const unsigned short* Bbase = B + (size_t)n0 * K + kOff;

  const int xr = (r32 & 7) << 3;
  int offA0[4], offA1[4], offB0[4], offB1[4];
#pragma unroll
  for (int ks = 0; ks < 4; ++ks) {
    const int gg = (((ks << 1) | kh) << 3) ^ xr;
    offA0[ks] = (wm      + r32) * LROW + gg;
    offA1[ks] = (wm + 32 + r32) * LROW + gg;
    offB0[ks] = (wn      + r32) * LROW + gg;
    offB1[ks] = (wn + 32 + r32) * LROW + gg;
  }

  f32x16 acc[2][2] = {};
  const int nk = kChunk >> 6;

#pragma unroll
  for (int h = 0; h < 4; ++h) gload16(Abase + gOff[h], &lA[dOff[h]]);
#pragma unroll
  for (int h = 0; h < 4; ++h) gload16(Bbase + gOff[h], &lB[dOff[h]]);
  __syncthreads();

  for (int kt = 0; kt < nk; ++kt) {
#pragma unroll
    for (int ks = 0; ks < 4; ++ks) {
      bf16x8 a0 = *(const bf16x8*)&lA[offA0[ks]];
      bf16x8 a1 = *(const bf16x8*)&lA[offA1[ks]];
      bf16x8 b0 = *(const bf16x8*)&lB[offB0[ks]];
      bf16x8 b1 = *(const bf16x8*)&lB[offB1[ks]];
      acc[0][0] = __builtin_amdgcn_mfma_f32_32x32x16_bf16(a0, b0, acc[0][0], 0, 0, 0);
      acc[0][1] = __builtin_amdgcn_mfma_f32_32x32x16_bf16(a0, b1, acc[0][1], 0, 0, 0);
      acc[1][0] = __builtin_amdgcn_mfma_f32_32x32x16_bf16(a1, b0, acc[1][0], 0, 0, 0);
      acc[1][1] = __builtin_amdgcn_mfma_f32_32x32x16_bf16(a1, b1, acc[1][1], 0, 0, 0);
    }
    if (kt + 1 < nk) {
      __syncthreads();
      const int ko = (kt + 1) << 6;
#pragma unroll
      for (int h = 0; h < 4; ++h) gload16(Abase + gOff[h] + ko, &lA[dOff[h]]);
#pragma unroll
      for (int h = 0; h < 4; ++h) gload16(Bbase + gOff[h] + ko, &lB[dOff[h]]);
      __syncthreads();
    }
  }

  if (MODE == 0) {
    unsigned short* C = (unsigned short*)Cout;
#pragma unroll
    for (int mi = 0; mi < 2; ++mi)
#pragma unroll
      for (int reg = 0; reg < 16; ++reg) {
        int m = m0 + wm + mi * 32 + (reg & 3) + ((reg >> 2) << 3) + (kh << 2);
#pragma unroll
        for (int ni = 0; ni < 2; ++ni) {
          int n = n0 + wn + ni * 32 + r32;
          C[(size_t)m * N + n] = f2bf(acc[mi][ni][reg] * alpha);
        }
      }
  } else if (MODE == 2) {
    float* C = (float*)Cout;
#pragma unroll
    for (int mi = 0; mi < 2; ++mi)
#pragma unroll
      for (int reg = 0; reg < 16; ++reg) {
        int m = m0 + wm + mi * 32 + (reg & 3) + ((reg >> 2) << 3) + (kh << 2);
        float inv = 1.0f / rowsum[m];
#pragma unroll
        for (int ni = 0; ni < 2; ++ni) {
          int n = n0 + wn + ni * 32 + r32;
          atomicAdd(&C[(size_t)m * N + n], acc[mi][ni][reg] * inv);
        }
      }
  }
}

extern "C" void kernel_launch(void* const* d_in, const int* in_sizes, int n_in,
                              void* d_out, int out_size, void* d_ws, size_t ws_size,
                              hipStream_t stream) {
  const float* x  = (const float*)d_in[0];
  const float* Wq = (const float*)d_in[1];
  const float* Wk = (const float*)d_in[2];
  const float* Wv = (const float*)d_in[3];

  char* ws = (char*)d_ws;
  unsigned short* xb     = (unsigned short*)(ws + 0);
  unsigned short* Qb     = (unsigned short*)(ws + 12582912);
  unsigned short* Kb     = (unsigned short*)(ws + 25165824);
  unsigned short* Vtb    = (unsigned short*)(ws + 37748736);
  unsigned short* wqb    = (unsigned short*)(ws + 50331648);
  unsigned short* wkb    = (unsigned short*)(ws + 51511296);
  unsigned short* wvb    = (unsigned short*)(ws + 52690944);
  float*          rowsum = (float*)(ws + 53870592);
  unsigned short* Pb     = (unsigned short*)(ws + 53903360);
  const size_t need = 53903360u + (size_t)SEQ * SEQ * 2u;
  if (ws_size < need) return;

  hipMemsetAsync(rowsum, 0, SEQ * sizeof(float), stream);
  hipMemsetAsync(d_out, 0, (size_t)out_size * sizeof(float), stream);

  // K0: all converts, one launch (NX + 3*NW float4s)
  const int n4_total = SEQ * DMODEL / 4 + 3 * (DMODEL * DMODEL / 4);
  convert_all<<<(n4_total + 255) / 256, 256, 0, stream>>>(
      x, Wq, Wk, Wv, xb, wqb, wkb, wvb);

  const float alpha_q = 0.03608439182435161f;  // 1/sqrt(768)
  // K1: fused Q/K/Vt projections, one launch (64 x 6 x 3 = 1152 blocks)
  gemm_bt<0><<<dim3(SEQ / 128, DMODEL / 128, 3), dim3(256), 0, stream>>>(
      xb, wqb, Qb, SEQ, DMODEL, DMODEL, alpha_q, nullptr, DMODEL,
      wkb, Kb, 1.0f, wvb, Vtb);
  // K2: 256^2 8-phase, exp + rowsum (1024 blocks)
  gemm256_exp<<<dim3(SEQ / 256, SEQ / 256), dim3(512), 0, stream>>>(
      Qb, Kb, Pb, SEQ, DMODEL, rowsum);
  // K3: 128^2 engine, split-K x8 (64 x 6 x 8 = 3072 blocks = 3 exact
  // rounds at 4-resident; fixes the 1.5-round 75%-utilization tail)
  gemm_bt<2><<<dim3(SEQ / 128, DMODEL / 128, KSPLIT), dim3(256), 0, stream>>>(
      Pb, Vtb, d_out, SEQ, DMODEL, SEQ, 1.0f, rowsum, SEQ / KSPLIT,
      nullptr, nullptr, 1.0f, nullptr, nullptr);
}

// Round 13
// 403.862 us; speedup vs baseline: 1.0672x; 1.0672x over previous
//
#include <hip/hip_runtime.h>
#include <stdint.h>

// Self-attention, SEQ=8192, D=768, single head.
//   K0 : fused convert x/Wq/Wk/Wv fp32->bf16 (one launch)
//   K1 : fused Q,K,Vt projections, z=3 (128^2 engine, MODE 0)
//   K2 : P' = exp(Q K^T) bf16 + rowsums     (256^2 8-phase engine)
//   K3 : out += (P' V)/rowsum, split-K x4   (128^2 engine, MODE 2)
//
// R23 = R20 restored exactly (best measured: 396 us). Session ledger:
//  - K3 variants: 128^2-KSPLIT4=156 BEST | KSPLIT8=198 (R22: backfill
//    model — no lockstep rounds; extra splits only add atomics+prologues)
//    | 256^2-8phase=230 (R18: 1-residency epilogue exposure) | T1=175
//    (R21: default mapping already P-panel-local since gx%8==0).
//  - K2 variants: 256^2-8phase=129 BEST (R17 invariants: 16x16x32 ->
//    8 acc chains, vmcnt(6) 3-half-tile flight, reg-held operands)
//    | 128^2=164 | T1 swizzle regresses.
//  - K1: fused z=3 single dispatch BEST (R20).
//  - Flash-fusion K2+K3 infeasible at D=768 (out-tile 256x768 fp32 =
//    384 regs/thread); P-in-fp8 predicted absmax ~1e-3 > tolerance.
// Noise band: identical code measured 392/396/406 across sessions (+-3-4%).

#define SEQ    8192
#define DMODEL 768
#define KSPLIT 4             // split-K for K3 (128^2 engine)
#define LROW   64            // 128^2 engine LDS row stride (halfwords)

typedef short bf16x8 __attribute__((ext_vector_type(8)));
typedef float f32x4  __attribute__((ext_vector_type(4)));
typedef float f32x16 __attribute__((ext_vector_type(16)));

__device__ __forceinline__ unsigned short f2bf(float f) {
  union { float f; unsigned int u; } v; v.f = f;
  unsigned int u = v.u;
  u += 0x7FFFu + ((u >> 16) & 1u);   // round-to-nearest-even
  return (unsigned short)(u >> 16);
}

// global -> LDS direct DMA, 16 B/lane; LDS dest wave-uniform + lane*16 (m104).
__device__ __forceinline__ void gload16(const unsigned short* g, unsigned short* l) {
  __builtin_amdgcn_global_load_lds(
      (const __attribute__((address_space(1))) unsigned int*)g,
      (__attribute__((address_space(3))) unsigned int*)l, 16, 0, 0);
}

// Stage one half-tile (128x64 bf16 = 16 KB): 512 thr x 2 x 16 B.
// LDS linear; source column pre-swizzled (slot j <- col j^(row&7)).
__device__ __forceinline__ void stage_ht(const unsigned short* __restrict__ g,
                                         int Kd, unsigned short* l, int t) {
  const int c0 = t, c1 = t + 512;
  const int r0 = c0 >> 3, r1 = c1 >> 3;
  const int s0 = ((c0 & 7) ^ (r0 & 7)) << 3;
  const int s1 = ((c1 & 7) ^ (r1 & 7)) << 3;
  gload16(g + (size_t)r0 * Kd + s0, l + (c0 << 3));
  gload16(g + (size_t)r1 * Kd + s1, l + (c1 << 3));
}

// K0: all four fp32->bf16 converts in one launch, range-decoded.
__global__ void convert_all(const float* __restrict__ x,  const float* __restrict__ Wq,
                            const float* __restrict__ Wk, const float* __restrict__ Wv,
                            unsigned short* __restrict__ xb,  unsigned short* __restrict__ wqb,
                            unsigned short* __restrict__ wkb, unsigned short* __restrict__ wvb) {
  const int NX = SEQ * DMODEL / 4;        // float4 count for x
  const int NW = DMODEL * DMODEL / 4;     // per weight
  int i = blockIdx.x * blockDim.x + threadIdx.x;
  const float* s; unsigned short* d; int off;
  if (i < NX)                { s = x;  d = xb;  off = i; }
  else if (i < NX + NW)      { s = Wq; d = wqb; off = i - NX; }
  else if (i < NX + 2 * NW)  { s = Wk; d = wkb; off = i - NX - NW; }
  else if (i < NX + 3 * NW)  { s = Wv; d = wvb; off = i - NX - 2 * NW; }
  else return;
  const float4 f = ((const float4*)s)[off];
  ushort4 o;
  o.x = f2bf(f.x); o.y = f2bf(f.y); o.z = f2bf(f.z); o.w = f2bf(f.w);
  ((ushort4*)d)[off] = o;
}

// ---------------- 256^2 8-phase engine (K2) ----------------
// C[m,n]=sum_k A[m,k]B[n,k]; writes exp(C) bf16 + atomic rowsums.
// 8 waves (2M x 4N); MFMA 16x16x32: A/B frag lane row=l&15, k=(l>>4)*8+j;
// C/D col=l&15, row=(l>>4)*4+reg [m89/m91].
// LDS halfwords: [dbuf2][tensor2][half2][128][64]=65536 (128 KB).
// Schedule (verified R17: K2 164->129 us): phases (qa, b-half) per K-tile,
// reads-once-into-regs, one 16KB stage/phase, vmcnt(6) only at ph4/ph8.
__launch_bounds__(512, 2)
__global__ void gemm256_exp(const unsigned short* __restrict__ A,
                            const unsigned short* __restrict__ B,
                            unsigned short* __restrict__ C,
                            int N, int K, float* __restrict__ rowsum) {
  __shared__ __align__(16) unsigned short lds[65536];
  const int t    = threadIdx.x;
  const int w    = t >> 6, l = t & 63;
  const int lr   = l & 15, lq = l >> 4;
  const int wrow = w >> 2, wcol = w & 3;
  const int m0   = blockIdx.x * 256;
  const int n0   = blockIdx.y * 256;
  const unsigned short* Ab = A + (size_t)m0 * K;
  const unsigned short* Bb = B + (size_t)n0 * K;

  const int rA64 = (wrow * 64 + lr) * 64;
  const int rB64 = (wcol * 32 + lr) * 64;
  const int x7   = lr & 7;
  const int csw0 = ((0 + lq) ^ x7) << 3;   // ks=0 chunk
  const int csw1 = ((4 + lq) ^ x7) << 3;   // ks=1 chunk

  f32x4 acc[2][2][4][2] = {};              // [qa][bh][rt][ct]
  const int nt = K >> 6, ni = nt >> 1;

#define STG(T, H, D, JT) stage_ht(((T) ? Bb : Ab) + (size_t)((H) * 128) * K + (JT) * 64, K, \
                                  &lds[(D) * 32768 + (T) * 16384 + (H) * 8192], t)
#define RDA(D, QA) do { \
    _Pragma("unroll") for (int rt = 0; rt < 4; ++rt) { \
      a[rt][0] = *(const bf16x8*)&lds[(D)*32768 + (QA)*8192 + rA64 + rt*1024 + csw0]; \
      a[rt][1] = *(const bf16x8*)&lds[(D)*32768 + (QA)*8192 + rA64 + rt*1024 + csw1]; \
    } } while (0)
#define RDB(D, BH, DST) do { \
    _Pragma("unroll") for (int ct = 0; ct < 2; ++ct) { \
      DST[ct][0] = *(const bf16x8*)&lds[(D)*32768 + 16384 + (BH)*8192 + rB64 + ct*1024 + csw0]; \
      DST[ct][1] = *(const bf16x8*)&lds[(D)*32768 + 16384 + (BH)*8192 + rB64 + ct*1024 + csw1]; \
    } } while (0)
#define MM16(QA, BH, BR) do { \
    __builtin_amdgcn_s_setprio(1); \
    _Pragma("unroll") for (int ks = 0; ks < 2; ++ks) \
      _Pragma("unroll") for (int rt = 0; rt < 4; ++rt) \
        _Pragma("unroll") for (int ct = 0; ct < 2; ++ct) \
          acc[QA][BH][rt][ct] = __builtin_amdgcn_mfma_f32_16x16x32_bf16( \
              a[rt][ks], BR[ct][ks], acc[QA][BH][rt][ct], 0, 0, 0); \
    __builtin_amdgcn_s_setprio(0); \
  } while (0)
#define WAITV6() asm volatile("s_waitcnt vmcnt(6)" ::: "memory")
#define WAITV0() asm volatile("s_waitcnt vmcnt(0)" ::: "memory")
#define LGKM0()  asm volatile("s_waitcnt lgkmcnt(0)" ::: "memory")
#define BAR()    __builtin_amdgcn_s_barrier()

  bf16x8 a[4][2], b0[2][2], b1[2][2];

  // Prologue: tile0 (A0,B0,B1,A1)->d0, tile1 (A0,B0,B1)->d1; drain to 3.
  STG(0, 0, 0, 0); STG(1, 0, 0, 0); STG(1, 1, 0, 0); STG(0, 1, 0, 0);
  STG(0, 0, 1, 1); STG(1, 0, 1, 1); STG(1, 1, 1, 1);
  WAITV6(); BAR();

  for (int i = 0; i < ni; ++i) {
    const int j = 2 * i;
    const bool full = (i + 1 < ni);
    // ph1 (d0, qa0, b0): 12 reads; stage d1.A1(j+1)
    RDA(0, 0); RDB(0, 0, b0); STG(0, 1, 1, j + 1);
    BAR(); LGKM0(); MM16(0, 0, b0); BAR();
    // ph2 (d0, qa0, b1): 4 reads; stage d0.A0(j+2)
    RDB(0, 1, b1); if (full) STG(0, 0, 0, j + 2);
    BAR(); LGKM0(); MM16(0, 1, b1); BAR();
    // ph3 (d0, qa1, b0): 8 reads; stage d0.B0(j+2)
    RDA(0, 1); if (full) STG(1, 0, 0, j + 2);
    BAR(); LGKM0(); MM16(1, 0, b0); BAR();
    // ph4 (d0, qa1, b1): 0 reads; stage d0.B1(j+2); counted wait AFTER MFMA
    if (full) STG(1, 1, 0, j + 2);
    BAR(); MM16(1, 1, b1);
    if (full) { WAITV6(); } else { WAITV0(); }
    BAR();
    // ph5 (d1, qa0, b0): 12 reads; stage d0.A1(j+2)
    RDA(1, 0); RDB(1, 0, b0); if (full) STG(0, 1, 0, j + 2);
    BAR(); LGKM0(); MM16(0, 0, b0); BAR();
    // ph6 (d1, qa0, b1): 4 reads; stage d1.A0(j+3)
    RDB(1, 1, b1); if (full) STG(0, 0, 1, j + 3);
    BAR(); LGKM0(); MM16(0, 1, b1); BAR();
    // ph7 (d1, qa1, b0): 8 reads; stage d1.B0(j+3)
    RDA(1, 1); if (full) STG(1, 0, 1, j + 3);
    BAR(); LGKM0(); MM16(1, 0, b0); BAR();
    // ph8 (d1, qa1, b1): 0 reads; stage d1.B1(j+3); counted wait
    if (full) STG(1, 1, 1, j + 3);
    BAR(); MM16(1, 1, b1);
    if (full) WAITV6();
    BAR();
  }

  // Epilogue: exp + bf16 store + per-row exp-sum (16-lane groups share m).
#pragma unroll
  for (int qa = 0; qa < 2; ++qa)
#pragma unroll
    for (int rt = 0; rt < 4; ++rt)
#pragma unroll
      for (int reg = 0; reg < 4; ++reg) {
        const int m = m0 + qa * 128 + wrow * 64 + rt * 16 + lq * 4 + reg;
        float s = 0.f;
#pragma unroll
        for (int bh = 0; bh < 2; ++bh)
#pragma unroll
          for (int ct = 0; ct < 2; ++ct) {
            const int n = n0 + bh * 128 + wcol * 32 + ct * 16 + lr;
            float p = __expf(acc[qa][bh][rt][ct][reg]);
            C[(size_t)m * N + n] = f2bf(p);
            s += p;
          }
#pragma unroll
        for (int off = 1; off < 16; off <<= 1) s += __shfl_xor(s, off, 64);
        if (lr == 0) atomicAdd(&rowsum[m], s);
      }
#undef STG
#undef RDA
#undef RDB
#undef MM16
#undef WAITV6
#undef WAITV0
#undef LGKM0
#undef BAR
}

// ---------------- 128^2 2-barrier engine (K1 fused / K3) ----------------
// MODE 0 (fused QKV projections, all K=768):
//   z=0: C = A·B^T       (Q = x Wq^T, alpha=1/sqrt(768), N=768)
//   z=1: C = A·B2^T      (K = x Wk^T, alpha=1, N=768)
//   z=2: C = A3·A^T      (Vt = Wv x^T, alpha=1, N=8192; bx/by swapped)
// MODE 2: split-K over z (kChunk each); atomicAdd fp32 C/rowsum[m] into Cout
template <int MODE>
__launch_bounds__(256, 4)
__global__ void gemm_bt(const unsigned short* __restrict__ A,
                        const unsigned short* __restrict__ B,
                        void* __restrict__ Cout,
                        int M, int N, int K, float alpha,
                        float* __restrict__ rowsum, int kChunk,
                        const unsigned short* __restrict__ B2,
                        void* __restrict__ Cout2, float alpha2,
                        const unsigned short* __restrict__ A3,
                        void* __restrict__ Cout3) {
  __shared__ __align__(16) unsigned short lA[128 * LROW];
  __shared__ __align__(16) unsigned short lB[128 * LROW];

  int bx = blockIdx.x, by = blockIdx.y;
  if (MODE == 0) {
    if (blockIdx.z == 1) { B = B2; Cout = Cout2; alpha = alpha2; }
    else if (blockIdx.z == 2) {
      B = A; A = A3; Cout = Cout3; alpha = 1.0f; N = SEQ;
      int tmp = bx; bx = by; by = tmp;   // m-tiles over 768, n-tiles over 8192
    }
  }
  const int kOff = (MODE == 2) ? blockIdx.z * kChunk : 0;

  const int t    = threadIdx.x;
  const int w    = t >> 6;
  const int l    = t & 63;
  const int r32  = l & 31;
  const int kh   = l >> 5;
  const int m0   = bx * 128;
  const int n0   = by * 128;
  const int wm   = (w & 1) * 64;
  const int wn   = (w >> 1) * 64;

  int gOff[4], dOff[4];
#pragma unroll
  for (int h = 0; h < 4; ++h) {
    int c   = t + (h << 8);
    int row = c >> 3;
    int j   = c & 7;
    gOff[h] = row * K + ((j ^ (row & 7)) << 3);
    dOff[h] = c << 3;
  }
  const unsigned short* Abase = A + (size_t)m0 * K + kOff;
  const unsigned short* Bbase = B + (size_t)n0 * K + kOff;

  const int xr = (r32 & 7) << 3;
  int offA0[4], offA1[4], offB0[4], offB1[4];
#pragma unroll
  for (int ks = 0; ks < 4; ++ks) {
    const int gg = (((ks << 1) | kh) << 3) ^ xr;
    offA0[ks] = (wm      + r32) * LROW + gg;
    offA1[ks] = (wm + 32 + r32) * LROW + gg;
    offB0[ks] = (wn      + r32) * LROW + gg;
    offB1[ks] = (wn + 32 + r32) * LROW + gg;
  }

  f32x16 acc[2][2] = {};
  const int nk = kChunk >> 6;

#pragma unroll
  for (int h = 0; h < 4; ++h) gload16(Abase + gOff[h], &lA[dOff[h]]);
#pragma unroll
  for (int h = 0; h < 4; ++h) gload16(Bbase + gOff[h], &lB[dOff[h]]);
  __syncthreads();

  for (int kt = 0; kt < nk; ++kt) {
#pragma unroll
    for (int ks = 0; ks < 4; ++ks) {
      bf16x8 a0 = *(const bf16x8*)&lA[offA0[ks]];
      bf16x8 a1 = *(const bf16x8*)&lA[offA1[ks]];
      bf16x8 b0 = *(const bf16x8*)&lB[offB0[ks]];
      bf16x8 b1 = *(const bf16x8*)&lB[offB1[ks]];
      acc[0][0] = __builtin_amdgcn_mfma_f32_32x32x16_bf16(a0, b0, acc[0][0], 0, 0, 0);
      acc[0][1] = __builtin_amdgcn_mfma_f32_32x32x16_bf16(a0, b1, acc[0][1], 0, 0, 0);
      acc[1][0] = __builtin_amdgcn_mfma_f32_32x32x16_bf16(a1, b0, acc[1][0], 0, 0, 0);
      acc[1][1] = __builtin_amdgcn_mfma_f32_32x32x16_bf16(a1, b1, acc[1][1], 0, 0, 0);
    }
    if (kt + 1 < nk) {
      __syncthreads();
      const int ko = (kt + 1) << 6;
#pragma unroll
      for (int h = 0; h < 4; ++h) gload16(Abase + gOff[h] + ko, &lA[dOff[h]]);
#pragma unroll
      for (int h = 0; h < 4; ++h) gload16(Bbase + gOff[h] + ko, &lB[dOff[h]]);
      __syncthreads();
    }
  }

  if (MODE == 0) {
    unsigned short* C = (unsigned short*)Cout;
#pragma unroll
    for (int mi = 0; mi < 2; ++mi)
#pragma unroll
      for (int reg = 0; reg < 16; ++reg) {
        int m = m0 + wm + mi * 32 + (reg & 3) + ((reg >> 2) << 3) + (kh << 2);
#pragma unroll
        for (int ni = 0; ni < 2; ++ni) {
          int n = n0 + wn + ni * 32 + r32;
          C[(size_t)m * N + n] = f2bf(acc[mi][ni][reg] * alpha);
        }
      }
  } else if (MODE == 2) {
    float* C = (float*)Cout;
#pragma unroll
    for (int mi = 0; mi < 2; ++mi)
#pragma unroll
      for (int reg = 0; reg < 16; ++reg) {
        int m = m0 + wm + mi * 32 + (reg & 3) + ((reg >> 2) << 3) + (kh << 2);
        float inv = 1.0f / rowsum[m];
#pragma unroll
        for (int ni = 0; ni < 2; ++ni) {
          int n = n0 + wn + ni * 32 + r32;
          atomicAdd(&C[(size_t)m * N + n], acc[mi][ni][reg] * inv);
        }
      }
  }
}

extern "C" void kernel_launch(void* const* d_in, const int* in_sizes, int n_in,
                              void* d_out, int out_size, void* d_ws, size_t ws_size,
                              hipStream_t stream) {
  const float* x  = (const float*)d_in[0];
  const float* Wq = (const float*)d_in[1];
  const float* Wk = (const float*)d_in[2];
  const float* Wv = (const float*)d_in[3];

  char* ws = (char*)d_ws;
  unsigned short* xb     = (unsigned short*)(ws + 0);
  unsigned short* Qb     = (unsigned short*)(ws + 12582912);
  unsigned short* Kb     = (unsigned short*)(ws + 25165824);
  unsigned short* Vtb    = (unsigned short*)(ws + 37748736);
  unsigned short* wqb    = (unsigned short*)(ws + 50331648);
  unsigned short* wkb    = (unsigned short*)(ws + 51511296);
  unsigned short* wvb    = (unsigned short*)(ws + 52690944);
  float*          rowsum = (float*)(ws + 53870592);
  unsigned short* Pb     = (unsigned short*)(ws + 53903360);
  const size_t need = 53903360u + (size_t)SEQ * SEQ * 2u;
  if (ws_size < need) return;

  hipMemsetAsync(rowsum, 0, SEQ * sizeof(float), stream);
  hipMemsetAsync(d_out, 0, (size_t)out_size * sizeof(float), stream);

  // K0: all converts, one launch (NX + 3*NW float4s)
  const int n4_total = SEQ * DMODEL / 4 + 3 * (DMODEL * DMODEL / 4);
  convert_all<<<(n4_total + 255) / 256, 256, 0, stream>>>(
      x, Wq, Wk, Wv, xb, wqb, wkb, wvb);

  const float alpha_q = 0.03608439182435161f;  // 1/sqrt(768)
  // K1: fused Q/K/Vt projections, one launch (64 x 6 x 3 = 1152 blocks)
  gemm_bt<0><<<dim3(SEQ / 128, DMODEL / 128, 3), dim3(256), 0, stream>>>(
      xb, wqb, Qb, SEQ, DMODEL, DMODEL, alpha_q, nullptr, DMODEL,
      wkb, Kb, 1.0f, wvb, Vtb);
  // K2: 256^2 8-phase, exp + rowsum (1024 blocks)
  gemm256_exp<<<dim3(SEQ / 256, SEQ / 256), dim3(512), 0, stream>>>(
      Qb, Kb, Pb, SEQ, DMODEL, rowsum);
  // K3: 128^2 engine, split-K x4 (64 x 6 x 4 = 1536 blocks)
  gemm_bt<2><<<dim3(SEQ / 128, DMODEL / 128, KSPLIT), dim3(256), 0, stream>>>(
      Pb, Vtb, d_out, SEQ, DMODEL, SEQ, 1.0f, rowsum, SEQ / KSPLIT,
      nullptr, nullptr, 1.0f, nullptr, nullptr);
}